// Round 1
// baseline (532.927 us; speedup 1.0000x reference)
//
#include <hip/hip_runtime.h>
#include <hip/hip_bf16.h>

#define DI __device__ __forceinline__

typedef float f32x4 __attribute__((ext_vector_type(4)));
typedef short s16x8 __attribute__((ext_vector_type(8)));

constexpr int N_NODES = 50000;
constexpr int N_EDGES = 400000;
constexpr int HC      = 320;   // H*C
constexpr int G       = 64;
constexpr int C       = 32;
constexpr float BN_EPS = 1e-5f;

// ---------------- workspace layout (bytes) ----------------
constexpr size_t OFF_WH    = 0;                                   // [960][128] bf16 (Wl,Wr,We)
constexpr size_t OFF_SCALE = 245760;                              // [128] f32
constexpr size_t OFF_SHIFT = OFF_SCALE + 512;                     // [128] f32
constexpr size_t OFF_Y     = OFF_SHIFT + 512;                     // [N][640] bf16 (xl|xr)
constexpr size_t OFF_ALPHA = OFF_Y + (size_t)N_NODES * 640 * 2;   // [E][10] f32 (exp(alpha))
constexpr size_t OFF_DENOM = OFF_ALPHA + (size_t)N_EDGES * 10 * 4;// [N][10] f32
constexpr size_t OFF_ACC   = OFF_DENOM + (size_t)N_NODES * 10 * 4;// [N][32] f32
constexpr size_t OFF_POOL  = OFF_ACC + (size_t)N_NODES * 32 * 4;  // [64][32] f32
constexpr size_t OFF_CNT   = OFF_POOL + (size_t)G * C * 4;        // [64] f32

DI float bf2f(unsigned short u) {
    unsigned int x = ((unsigned int)u) << 16;
    float f; __builtin_memcpy(&f, &x, 4); return f;
}
DI unsigned short f2bf(float f) {   // round-to-nearest-even (finite inputs)
    unsigned int x; __builtin_memcpy(&x, &f, 4);
    x += 0x7FFFu + ((x >> 16) & 1u);
    return (unsigned short)(x >> 16);
}
DI float lrelu(float v) { return v > 0.f ? v : 0.2f * v; }
// XOR swizzle inside a 256B row: kills the stride-256B bank conflict on frag reads
DI int swz(int row, int kb) { return row * 256 + (kb ^ ((row & 7) << 4)); }

// ---------------- init: zero accumulators, convert weights, BN scale/shift ----
__global__ void k_init(const float* __restrict__ Wl, const float* __restrict__ Wr,
                       const float* __restrict__ We, const float* __restrict__ gamma,
                       const float* __restrict__ beta, const float* __restrict__ mean,
                       const float* __restrict__ var,
                       unsigned short* __restrict__ Wh, float* __restrict__ scale,
                       float* __restrict__ shift, float* __restrict__ denom,
                       float* __restrict__ accC, float* __restrict__ pooled,
                       float* __restrict__ cnt)
{
    int idx0 = blockIdx.x * blockDim.x + threadIdx.x;
    int stride = gridDim.x * blockDim.x;
    for (int i = idx0; i < 960 * 128; i += stride) {
        float v;
        if (i < 320 * 128)      v = Wl[i];
        else if (i < 640 * 128) v = Wr[i - 320 * 128];
        else                    v = We[i - 640 * 128];
        Wh[i] = f2bf(v);
    }
    for (int i = idx0; i < 128; i += stride) {
        float sc = gamma[i] * rsqrtf(var[i] + BN_EPS);
        scale[i] = sc;
        shift[i] = beta[i] - mean[i] * sc;
    }
    for (int i = idx0; i < N_NODES * 10; i += stride) denom[i] = 0.f;
    for (int i = idx0; i < N_NODES * 32; i += stride) accC[i] = 0.f;
    for (int i = idx0; i < G * C; i += stride) pooled[i] = 0.f;
    for (int i = idx0; i < G; i += stride) cnt[i] = 0.f;
}

// ---------------- node GEMM: y[n, 0:640] = bn(x) @ [Wl;Wr].T + [bl;br] (bf16 out)
__global__ __launch_bounds__(512)
void k_node_gemm(const float* __restrict__ x, const unsigned short* __restrict__ Wh,
                 const float* __restrict__ scale, const float* __restrict__ shift,
                 const float* __restrict__ bl, const float* __restrict__ br,
                 unsigned short* __restrict__ y)
{
    __shared__ unsigned char smem[16384 + 81920]; // A: 64x128 bf16, B: 320x128 bf16
    unsigned char* sA = smem;
    unsigned char* sB = smem + 16384;
    const int tid = threadIdx.x;
    const int n0 = blockIdx.x * 64;
    const int ch = blockIdx.y;            // 0: Wl half, 1: Wr half
    const int wrow0 = ch * 320;

    // stage A (x with BN fused), fp32 -> bf16
#pragma unroll
    for (int it = 0; it < 4; ++it) {
        int c = tid + it * 512;           // 0..2047
        int row = c >> 5, q = c & 31;
        int n = n0 + row;
        float4 v = make_float4(0.f, 0.f, 0.f, 0.f);
        if (n < N_NODES) v = *reinterpret_cast<const float4*>(x + (size_t)n * 128 + q * 4);
        unsigned long long pk = 0;
        const float* vp = reinterpret_cast<const float*>(&v);
#pragma unroll
        for (int i = 0; i < 4; ++i) {
            float xv = vp[i] * scale[q * 4 + i] + shift[q * 4 + i];
            pk |= ((unsigned long long)f2bf(xv)) << (16 * i);
        }
        *reinterpret_cast<unsigned long long*>(sA + swz(row, q * 8)) = pk;
    }
    // stage B (already bf16)
#pragma unroll
    for (int it = 0; it < 10; ++it) {
        int c = tid + it * 512;           // 0..5119
        int row = c >> 4, q = c & 15;
        uint4 v = *reinterpret_cast<const uint4*>(Wh + (size_t)(wrow0 + row) * 128 + q * 8);
        *reinterpret_cast<uint4*>(sB + swz(row, q * 16)) = v;
    }
    __syncthreads();

    const int w = tid >> 6, l = tid & 63;
    const int rw = (w & 3) * 16;          // wave rows in tile
    const int cq = (w >> 2) * 160;        // wave cols in tile
    const int l15 = l & 15, l4 = l >> 4;

    f32x4 acc[10];
#pragma unroll
    for (int f = 0; f < 10; ++f) acc[f] = (f32x4){0.f, 0.f, 0.f, 0.f};

#pragma unroll
    for (int kk = 0; kk < 4; ++kk) {
        int kb = kk * 64 + l4 * 16;
        s16x8 a = *reinterpret_cast<const s16x8*>(sA + swz(rw + l15, kb));
#pragma unroll
        for (int f = 0; f < 10; ++f) {
            s16x8 b = *reinterpret_cast<const s16x8*>(sB + swz(cq + f * 16 + l15, kb));
            acc[f] = __builtin_amdgcn_mfma_f32_16x16x32_bf16(a, b, acc[f], 0, 0, 0);
        }
    }

    const float* bias = ch ? br : bl;
#pragma unroll
    for (int f = 0; f < 10; ++f) {
        int lc = cq + f * 16 + l15;       // 0..319 within half
        float bv = bias[lc];
        int col = ch * 320 + lc;          // 0..639
#pragma unroll
        for (int j = 0; j < 4; ++j) {
            int n = n0 + rw + l4 * 4 + j;
            if (n < N_NODES)
                y[(size_t)n * 640 + col] = f2bf(acc[f][j] + bv);
        }
    }
}

// ---------------- edge GEMM + GATv2 scoring epilogue ----------------
// ea = edge_attr @ We.T; alpha[e,h] = sum_c att[h,c]*lrelu(ea+xl[src]+xr[dst]);
// writes exp(alpha) and atomic-accumulates denom[dst,h]
__global__ __launch_bounds__(512)
void k_edge(const float* __restrict__ eattr, const unsigned short* __restrict__ Wh,
            const unsigned short* __restrict__ y, const int* __restrict__ ei,
            const float* __restrict__ att, float* __restrict__ alphaE,
            float* __restrict__ denom)
{
    __shared__ unsigned char smem[16384 + 81920]; // A: 64x128, B(We): 320x128 bf16
    unsigned char* sA = smem;
    unsigned char* sB = smem + 16384;
    const int tid = threadIdx.x;
    const int e0 = blockIdx.x * 64;

#pragma unroll
    for (int it = 0; it < 4; ++it) {
        int c = tid + it * 512;
        int row = c >> 5, q = c & 31;
        float4 v = *reinterpret_cast<const float4*>(eattr + (size_t)(e0 + row) * 128 + q * 4);
        const float* vp = reinterpret_cast<const float*>(&v);
        unsigned long long pk = 0;
#pragma unroll
        for (int i = 0; i < 4; ++i) pk |= ((unsigned long long)f2bf(vp[i])) << (16 * i);
        *reinterpret_cast<unsigned long long*>(sA + swz(row, q * 8)) = pk;
    }
#pragma unroll
    for (int it = 0; it < 10; ++it) {
        int c = tid + it * 512;
        int row = c >> 4, q = c & 15;
        uint4 v = *reinterpret_cast<const uint4*>(Wh + (size_t)(640 + row) * 128 + q * 8);
        *reinterpret_cast<uint4*>(sB + swz(row, q * 16)) = v;
    }
    __syncthreads();

    const int w = tid >> 6, l = tid & 63;
    const int rw = (w & 3) * 16;
    const int ch = w >> 2;                // head-half: heads [ch*5, ch*5+5)
    const int cq = ch * 160;
    const int l15 = l & 15, l4 = l >> 4;

    f32x4 acc[10];
#pragma unroll
    for (int f = 0; f < 10; ++f) acc[f] = (f32x4){0.f, 0.f, 0.f, 0.f};

#pragma unroll
    for (int kk = 0; kk < 4; ++kk) {
        int kb = kk * 64 + l4 * 16;
        s16x8 a = *reinterpret_cast<const s16x8*>(sA + swz(rw + l15, kb));
#pragma unroll
        for (int f = 0; f < 10; ++f) {
            s16x8 b = *reinterpret_cast<const s16x8*>(sB + swz(cq + f * 16 + l15, kb));
            acc[f] = __builtin_amdgcn_mfma_f32_16x16x32_bf16(a, b, acc[f], 0, 0, 0);
        }
    }

    // epilogue: rows e = e0 + rw + l4*4 + j
    int srcj[4], dstj[4];
#pragma unroll
    for (int j = 0; j < 4; ++j) {
        int e = e0 + rw + l4 * 4 + j;
        srcj[j] = ei[e];
        dstj[j] = ei[N_EDGES + e];
    }
#pragma unroll
    for (int hl = 0; hl < 5; ++hl) {
        int hg = ch * 5 + hl;             // global head
        float a0 = att[hg * 32 + l15];
        float a1 = att[hg * 32 + 16 + l15];
        int hc0 = hg * 32 + l15;          // col within [0,320)
        int hc1 = hc0 + 16;
#pragma unroll
        for (int j = 0; j < 4; ++j) {
            float m0 = acc[2 * hl][j]
                     + bf2f(y[(size_t)srcj[j] * 640 + hc0])
                     + bf2f(y[(size_t)dstj[j] * 640 + 320 + hc0]);
            float m1 = acc[2 * hl + 1][j]
                     + bf2f(y[(size_t)srcj[j] * 640 + hc1])
                     + bf2f(y[(size_t)dstj[j] * 640 + 320 + hc1]);
            float v = a0 * lrelu(m0) + a1 * lrelu(m1);
            v += __shfl_xor(v, 1);
            v += __shfl_xor(v, 2);
            v += __shfl_xor(v, 4);
            v += __shfl_xor(v, 8);
            float ev = __expf(v);         // no max-shift: |v| <~ 3, safe in fp32
            if (l15 == 0) {
                int e = e0 + rw + l4 * 4 + j;
                alphaE[(size_t)e * 10 + hg] = ev;
                atomicAdd(&denom[(size_t)dstj[j] * 10 + hg], ev);
            }
        }
    }
}

// ---------------- aggregation: accC[dst,c] += sum_h xl[src,h,c]*alpha_norm ----
__global__ __launch_bounds__(256)
void k_agg(const float* __restrict__ alphaE, const float* __restrict__ denom,
           const unsigned short* __restrict__ y, const int* __restrict__ ei,
           float* __restrict__ accC)
{
    const int lane = threadIdx.x & 63;
    const int wid = (blockIdx.x * blockDim.x + threadIdx.x) >> 6;
    const int nw = (gridDim.x * blockDim.x) >> 6;
    const int g = lane >> 5, c = lane & 31;
    for (int e = wid; e < N_EDGES; e += nw) {
        int src = ei[e];
        int dst = ei[N_EDGES + e];
        float wv = 0.f;
        if (lane < 10)
            wv = alphaE[(size_t)e * 10 + lane] / (denom[(size_t)dst * 10 + lane] + 1e-16f);
        float s = 0.f;
#pragma unroll
        for (int i = 0; i < 5; ++i) {
            int h = g * 5 + i;
            float whv = __shfl(wv, h);
            s += whv * bf2f(y[(size_t)src * 640 + h * 32 + c]);
        }
        float other = __shfl_down(s, 32);
        if (lane < 32) atomicAdd(&accC[(size_t)dst * 32 + c], s + other);
    }
}

// ---------------- per-node finish + per-graph mean pool (LDS-buffered) -------
__global__ __launch_bounds__(256)
void k_pool(const float* __restrict__ accC, const float* __restrict__ bias_out,
            const int* __restrict__ batch, float* __restrict__ pooled,
            float* __restrict__ cnt)
{
    __shared__ float sm[G * C];
    __shared__ float smc[G];
    int tid = threadIdx.x;
    for (int i = tid; i < G * C; i += 256) sm[i] = 0.f;
    if (tid < G) smc[tid] = 0.f;
    __syncthreads();
    int base = blockIdx.x * 2048;
    for (int it = 0; it < 8; ++it) {
        int idx = base + it * 256 + tid;
        if (idx < N_NODES * C) {
            int n = idx >> 5, c = idx & 31;
            float v = accC[idx] * 0.1f + bias_out[c];   // mean over 10 heads + bias
            v = fmaxf(v, 0.f);                          // relu
            int gr = batch[n];
            atomicAdd(&sm[gr * C + c], v);
            if (c == 0) atomicAdd(&smc[gr], 1.f);
        }
    }
    __syncthreads();
    for (int i = tid; i < G * C; i += 256)
        if (sm[i] != 0.f) atomicAdd(&pooled[i], sm[i]);
    if (tid < G && smc[tid] != 0.f) atomicAdd(&cnt[tid], smc[tid]);
}

// ---------------- final tiny classifier ----------------
__global__ void k_final(const float* __restrict__ pooled, const float* __restrict__ cnt,
                        const float* __restrict__ Wlin, const float* __restrict__ blin,
                        float* __restrict__ out)
{
    int g = threadIdx.x;
    if (g >= G) return;
    float cg = fmaxf(cnt[g], 1.f);
    float s0 = blin[0], s1 = blin[1];
#pragma unroll
    for (int c = 0; c < C; ++c) {
        float p = pooled[g * C + c] / cg;
        s0 += p * Wlin[c];
        s1 += p * Wlin[C + c];
    }
    out[g * 2 + 0] = s0;
    out[g * 2 + 1] = s1;
}

extern "C" void kernel_launch(void* const* d_in, const int* in_sizes, int n_in,
                              void* d_out, int out_size, void* d_ws, size_t ws_size,
                              hipStream_t stream)
{
    const float* x         = (const float*)d_in[0];
    const float* edge_attr = (const float*)d_in[1];
    const float* bn_gamma  = (const float*)d_in[2];
    const float* bn_beta   = (const float*)d_in[3];
    const float* bn_mean   = (const float*)d_in[4];
    const float* bn_var    = (const float*)d_in[5];
    const float* Wl        = (const float*)d_in[6];
    const float* bl        = (const float*)d_in[7];
    const float* Wr        = (const float*)d_in[8];
    const float* br        = (const float*)d_in[9];
    const float* We        = (const float*)d_in[10];
    const float* att       = (const float*)d_in[11];
    const float* bias_out  = (const float*)d_in[12];
    const float* Wlin      = (const float*)d_in[13];
    const float* blin      = (const float*)d_in[14];
    const int* edge_index  = (const int*)d_in[15];
    const int* batch       = (const int*)d_in[16];
    float* out = (float*)d_out;

    char* ws = (char*)d_ws;
    unsigned short* Wh    = (unsigned short*)(ws + OFF_WH);
    float* scale          = (float*)(ws + OFF_SCALE);
    float* shift          = (float*)(ws + OFF_SHIFT);
    unsigned short* y     = (unsigned short*)(ws + OFF_Y);
    float* alphaE         = (float*)(ws + OFF_ALPHA);
    float* denom          = (float*)(ws + OFF_DENOM);
    float* accC           = (float*)(ws + OFF_ACC);
    float* pooled         = (float*)(ws + OFF_POOL);
    float* cnt            = (float*)(ws + OFF_CNT);

    k_init<<<1024, 256, 0, stream>>>(Wl, Wr, We, bn_gamma, bn_beta, bn_mean, bn_var,
                                     Wh, scale, shift, denom, accC, pooled, cnt);
    k_node_gemm<<<dim3(782, 2), 512, 0, stream>>>(x, Wh, scale, shift, bl, br, y);
    k_edge<<<6250, 512, 0, stream>>>(edge_attr, Wh, y, edge_index, att, alphaE, denom);
    k_agg<<<2048, 256, 0, stream>>>(alphaE, denom, y, edge_index, accC);
    k_pool<<<782, 256, 0, stream>>>(accC, bias_out, batch, pooled, cnt);
    k_final<<<1, 64, 0, stream>>>(pooled, cnt, Wlin, blin, out);
}

// Round 2
// 292.357 us; speedup vs baseline: 1.8229x; 1.8229x over previous
//
#include <hip/hip_runtime.h>
#include <hip/hip_bf16.h>

#define DI __device__ __forceinline__

typedef float f32x4 __attribute__((ext_vector_type(4)));
typedef short s16x8 __attribute__((ext_vector_type(8)));

constexpr int N_NODES = 50000;
constexpr int N_EDGES = 400000;
constexpr int G       = 64;
constexpr int C       = 32;
constexpr float BN_EPS = 1e-5f;

// ---------------- workspace layout (bytes) ----------------
constexpr size_t OFF_WH    = 0;                                   // [960][128] bf16 (Wl,Wr,We)
constexpr size_t OFF_SCALE = 245760;                              // [128] f32
constexpr size_t OFF_SHIFT = OFF_SCALE + 512;                     // [128] f32
constexpr size_t OFF_Y     = OFF_SHIFT + 512;                     // [N][640] bf16 (xl|xr)
constexpr size_t OFF_ALPHA = OFF_Y + (size_t)N_NODES * 640 * 2;   // [E][10] f32 (exp(alpha))
constexpr size_t OFF_DENOM = OFF_ALPHA + (size_t)N_EDGES * 10 * 4;// [N][10] f32
constexpr size_t OFF_ACC   = OFF_DENOM + (size_t)N_NODES * 10 * 4;// [N][32] f32
constexpr size_t OFF_POOL  = OFF_ACC + (size_t)N_NODES * 32 * 4;  // [64][32] f32
constexpr size_t OFF_CNT   = OFF_POOL + (size_t)G * C * 4;        // [64] f32

DI float bf2f(unsigned short u) {
    unsigned int x = ((unsigned int)u) << 16;
    float f; __builtin_memcpy(&f, &x, 4); return f;
}
DI unsigned short f2bf(float f) {   // round-to-nearest-even (finite inputs)
    unsigned int x; __builtin_memcpy(&x, &f, 4);
    x += 0x7FFFu + ((x >> 16) & 1u);
    return (unsigned short)(x >> 16);
}
DI float lrelu(float v) { return v > 0.f ? v : 0.2f * v; }
// XOR swizzle inside a 256B row (A tile: row stride 256B)
DI int swzA(int row, int kb) { return row * 256 + (kb ^ ((row & 7) << 4)); }
// B tile [320][64] bf16: row stride 128B
DI int swzB(int row, int kb) { return row * 128 + (kb ^ ((row & 7) << 4)); }

// ---------------- init ----------------
__global__ void k_init(const float* __restrict__ Wl, const float* __restrict__ Wr,
                       const float* __restrict__ We, const float* __restrict__ gamma,
                       const float* __restrict__ beta, const float* __restrict__ mean,
                       const float* __restrict__ var,
                       unsigned short* __restrict__ Wh, float* __restrict__ scale,
                       float* __restrict__ shift, float* __restrict__ denom,
                       float* __restrict__ accC, float* __restrict__ pooled,
                       float* __restrict__ cnt)
{
    int idx0 = blockIdx.x * blockDim.x + threadIdx.x;
    int stride = gridDim.x * blockDim.x;
    for (int i = idx0; i < 960 * 128; i += stride) {
        float v;
        if (i < 320 * 128)      v = Wl[i];
        else if (i < 640 * 128) v = Wr[i - 320 * 128];
        else                    v = We[i - 640 * 128];
        Wh[i] = f2bf(v);
    }
    for (int i = idx0; i < 128; i += stride) {
        float sc = gamma[i] * rsqrtf(var[i] + BN_EPS);
        scale[i] = sc;
        shift[i] = beta[i] - mean[i] * sc;
    }
    for (int i = idx0; i < N_NODES * 10; i += stride) denom[i] = 0.f;
    for (int i = idx0; i < N_NODES * 32; i += stride) accC[i] = 0.f;
    for (int i = idx0; i < G * C; i += stride) pooled[i] = 0.f;
    for (int i = idx0; i < G; i += stride) cnt[i] = 0.f;
}

// ---------------- node GEMM: y[n, 0:640] = bn(x) @ [Wl;Wr].T + [bl;br] ----
__global__ __launch_bounds__(512)
void k_node_gemm(const float* __restrict__ x, const unsigned short* __restrict__ Wh,
                 const float* __restrict__ scale, const float* __restrict__ shift,
                 const float* __restrict__ bl, const float* __restrict__ br,
                 unsigned short* __restrict__ y)
{
    __shared__ unsigned char smem[16384 + 40960]; // A: 64x128 bf16; B half: 320x64 bf16
    unsigned char* sA = smem;
    unsigned char* sB = smem + 16384;
    const int tid = threadIdx.x;
    const int n0 = blockIdx.x * 64;
    const int ch = blockIdx.y;            // 0: Wl half, 1: Wr half
    const int wrow0 = ch * 320;

    // stage A (x with BN fused), fp32 -> bf16
#pragma unroll
    for (int it = 0; it < 4; ++it) {
        int c = tid + it * 512;           // 0..2047
        int row = c >> 5, q = c & 31;
        int n = n0 + row;
        float4 v = make_float4(0.f, 0.f, 0.f, 0.f);
        if (n < N_NODES) v = *reinterpret_cast<const float4*>(x + (size_t)n * 128 + q * 4);
        unsigned long long pk = 0;
        const float* vp = reinterpret_cast<const float*>(&v);
#pragma unroll
        for (int i = 0; i < 4; ++i) {
            float xv = vp[i] * scale[q * 4 + i] + shift[q * 4 + i];
            pk |= ((unsigned long long)f2bf(xv)) << (16 * i);
        }
        *reinterpret_cast<unsigned long long*>(sA + swzA(row, q * 8)) = pk;
    }

    const int w = tid >> 6, l = tid & 63;
    const int rw = (w & 3) * 16;
    const int cq = (w >> 2) * 160;
    const int l15 = l & 15, l4 = l >> 4;

    f32x4 acc[10];
#pragma unroll
    for (int f = 0; f < 10; ++f) acc[f] = (f32x4){0.f, 0.f, 0.f, 0.f};

    for (int half = 0; half < 2; ++half) {
        if (half) __syncthreads();        // mfma of prev half done reading sB
#pragma unroll
        for (int it = 0; it < 5; ++it) {
            int c = tid + it * 512;       // 0..2559
            int row = c >> 3, q = c & 7;
            uint4 v = *reinterpret_cast<const uint4*>(
                Wh + (size_t)(wrow0 + row) * 128 + half * 64 + q * 8);
            *reinterpret_cast<uint4*>(sB + swzB(row, q * 16)) = v;
        }
        __syncthreads();
#pragma unroll
        for (int kkh = 0; kkh < 2; ++kkh) {
            int kb = kkh * 64 + l4 * 16;
            s16x8 a = *reinterpret_cast<const s16x8*>(sA + swzA(rw + l15, half * 128 + kb));
#pragma unroll
            for (int f = 0; f < 10; ++f) {
                s16x8 b = *reinterpret_cast<const s16x8*>(sB + swzB(cq + f * 16 + l15, kb));
                acc[f] = __builtin_amdgcn_mfma_f32_16x16x32_bf16(a, b, acc[f], 0, 0, 0);
            }
        }
    }

    const float* bias = ch ? br : bl;
#pragma unroll
    for (int f = 0; f < 10; ++f) {
        int lc = cq + f * 16 + l15;
        float bv = bias[lc];
        int col = ch * 320 + lc;
#pragma unroll
        for (int j = 0; j < 4; ++j) {
            int n = n0 + rw + l4 * 4 + j;
            if (n < N_NODES)
                y[(size_t)n * 640 + col] = f2bf(acc[f][j] + bv);
        }
    }
}

// ---------------- edge GEMM + GATv2 scoring (wave-per-edge epilogue) ---------
__global__ __launch_bounds__(512)
void k_edge(const float* __restrict__ eattr, const unsigned short* __restrict__ Wh,
            const unsigned short* __restrict__ y, const int* __restrict__ ei,
            const float* __restrict__ att, float* __restrict__ alphaE,
            float* __restrict__ denom)
{
    __shared__ unsigned char smem[16384 + 40960]; // A 16KB; B half 40KB (reused as ea)
    unsigned char* sA = smem;
    unsigned char* sB = smem + 16384;
    unsigned char* sE = smem + 16384;             // ea [64][320] bf16, after MFMA
    const int tid = threadIdx.x;
    const int e0 = blockIdx.x * 64;
    const int w = tid >> 6, l = tid & 63;
    const int rw = (w & 3) * 16;
    const int cq = (w >> 2) * 160;
    const int l15 = l & 15, l4 = l >> 4;

    // preload att (per-lane 8 consecutive cols) and this wave's edge endpoints
    float attreg[8];
    if (l < 40) {
        float4 a0 = *reinterpret_cast<const float4*>(att + l * 8);
        float4 a1 = *reinterpret_cast<const float4*>(att + l * 8 + 4);
        attreg[0] = a0.x; attreg[1] = a0.y; attreg[2] = a0.z; attreg[3] = a0.w;
        attreg[4] = a1.x; attreg[5] = a1.y; attreg[6] = a1.z; attreg[7] = a1.w;
    }
    int idxv = 0;
    if (l < 8)       idxv = ei[e0 + w * 8 + l];
    else if (l < 16) idxv = ei[N_EDGES + e0 + w * 8 + (l - 8)];

    // stage A (edge_attr fp32 -> bf16); E = 6250*64 exactly, no bounds needed
#pragma unroll
    for (int it = 0; it < 4; ++it) {
        int c = tid + it * 512;
        int row = c >> 5, q = c & 31;
        float4 v = *reinterpret_cast<const float4*>(eattr + (size_t)(e0 + row) * 128 + q * 4);
        const float* vp = reinterpret_cast<const float*>(&v);
        unsigned long long pk = 0;
#pragma unroll
        for (int i = 0; i < 4; ++i) pk |= ((unsigned long long)f2bf(vp[i])) << (16 * i);
        *reinterpret_cast<unsigned long long*>(sA + swzA(row, q * 8)) = pk;
    }

    f32x4 acc[10];
#pragma unroll
    for (int f = 0; f < 10; ++f) acc[f] = (f32x4){0.f, 0.f, 0.f, 0.f};

    for (int half = 0; half < 2; ++half) {
        if (half) __syncthreads();
#pragma unroll
        for (int it = 0; it < 5; ++it) {
            int c = tid + it * 512;
            int row = c >> 3, q = c & 7;
            uint4 v = *reinterpret_cast<const uint4*>(
                Wh + (size_t)(640 + row) * 128 + half * 64 + q * 8);
            *reinterpret_cast<uint4*>(sB + swzB(row, q * 16)) = v;
        }
        __syncthreads();
#pragma unroll
        for (int kkh = 0; kkh < 2; ++kkh) {
            int kb = kkh * 64 + l4 * 16;
            s16x8 a = *reinterpret_cast<const s16x8*>(sA + swzA(rw + l15, half * 128 + kb));
#pragma unroll
            for (int f = 0; f < 10; ++f) {
                s16x8 b = *reinterpret_cast<const s16x8*>(sB + swzB(cq + f * 16 + l15, kb));
                acc[f] = __builtin_amdgcn_mfma_f32_16x16x32_bf16(a, b, acc[f], 0, 0, 0);
            }
        }
    }
    __syncthreads();   // all waves done reading sB -> safe to overwrite with ea

    // spill ea (bf16, XOR-swizzled 16B chunks) to LDS
#pragma unroll
    for (int f = 0; f < 10; ++f) {
        int col = cq + f * 16 + l15;
#pragma unroll
        for (int j = 0; j < 4; ++j) {
            int row = rw + l4 * 4 + j;
            *reinterpret_cast<unsigned short*>(
                sE + row * 640 + ((col * 2) ^ ((row & 7) << 4))) = f2bf(acc[f][j]);
        }
    }
    __syncthreads();

    // scoring: each wave owns 8 edges; 40 lanes x 8 cols each
#pragma unroll 2
    for (int p = 0; p < 8; ++p) {
        int src = __shfl(idxv, p);
        int dst = __shfl(idxv, 8 + p);
        int row = w * 8 + p;
        float partial = 0.f;
        if (l < 40) {
            s16x8 ev  = *reinterpret_cast<const s16x8*>(
                sE + row * 640 + ((l * 16) ^ ((row & 7) << 4)));
            s16x8 xlv = *reinterpret_cast<const s16x8*>(y + (size_t)src * 640 + l * 8);
            s16x8 xrv = *reinterpret_cast<const s16x8*>(y + (size_t)dst * 640 + 320 + l * 8);
#pragma unroll
            for (int i = 0; i < 8; ++i) {
                float m = bf2f((unsigned short)ev[i]) + bf2f((unsigned short)xlv[i])
                        + bf2f((unsigned short)xrv[i]);
                partial += attreg[i] * lrelu(m);
            }
        }
        partial += __shfl_xor(partial, 1);
        partial += __shfl_xor(partial, 2);
        if (l < 40 && (l & 3) == 0) {
            float ex = __expf(partial);
            int e = e0 + row;
            alphaE[(size_t)e * 10 + (l >> 2)] = ex;
            atomicAdd(&denom[(size_t)dst * 10 + (l >> 2)], ex);
        }
    }
}

// ---------------- aggregation: accC[dst,c] += sum_h xl[src,h,c]*alpha_norm ----
__global__ __launch_bounds__(256)
void k_agg(const float* __restrict__ alphaE, const float* __restrict__ denom,
           const unsigned short* __restrict__ y, const int* __restrict__ ei,
           float* __restrict__ accC)
{
    const int lane = threadIdx.x & 63;
    const int wid = (blockIdx.x * blockDim.x + threadIdx.x) >> 6;
    const int nw = (gridDim.x * blockDim.x) >> 6;
    const int g = lane >> 5, c = lane & 31;
    for (int e = wid; e < N_EDGES; e += nw) {
        int src = ei[e];
        int dst = ei[N_EDGES + e];
        float wv = 0.f;
        if (lane < 10)
            wv = alphaE[(size_t)e * 10 + lane] / (denom[(size_t)dst * 10 + lane] + 1e-16f);
        float s = 0.f;
#pragma unroll
        for (int i = 0; i < 5; ++i) {
            int h = g * 5 + i;
            float whv = __shfl(wv, h);
            s += whv * bf2f(y[(size_t)src * 640 + h * 32 + c]);
        }
        float other = __shfl_down(s, 32);
        if (lane < 32) atomicAdd(&accC[(size_t)dst * 32 + c], s + other);
    }
}

// ---------------- per-node finish + per-graph mean pool ----------------
__global__ __launch_bounds__(256)
void k_pool(const float* __restrict__ accC, const float* __restrict__ bias_out,
            const int* __restrict__ batch, float* __restrict__ pooled,
            float* __restrict__ cnt)
{
    __shared__ float sm[G * C];
    __shared__ float smc[G];
    int tid = threadIdx.x;
    for (int i = tid; i < G * C; i += 256) sm[i] = 0.f;
    if (tid < G) smc[tid] = 0.f;
    __syncthreads();
    int base = blockIdx.x * 2048;
    for (int it = 0; it < 8; ++it) {
        int idx = base + it * 256 + tid;
        if (idx < N_NODES * C) {
            int n = idx >> 5, c = idx & 31;
            float v = accC[idx] * 0.1f + bias_out[c];
            v = fmaxf(v, 0.f);
            int gr = batch[n];
            atomicAdd(&sm[gr * C + c], v);
            if (c == 0) atomicAdd(&smc[gr], 1.f);
        }
    }
    __syncthreads();
    for (int i = tid; i < G * C; i += 256)
        if (sm[i] != 0.f) atomicAdd(&pooled[i], sm[i]);
    if (tid < G && smc[tid] != 0.f) atomicAdd(&cnt[tid], smc[tid]);
}

// ---------------- final tiny classifier ----------------
__global__ void k_final(const float* __restrict__ pooled, const float* __restrict__ cnt,
                        const float* __restrict__ Wlin, const float* __restrict__ blin,
                        float* __restrict__ out)
{
    int g = threadIdx.x;
    if (g >= G) return;
    float cg = fmaxf(cnt[g], 1.f);
    float s0 = blin[0], s1 = blin[1];
#pragma unroll
    for (int c = 0; c < C; ++c) {
        float p = pooled[g * C + c] / cg;
        s0 += p * Wlin[c];
        s1 += p * Wlin[C + c];
    }
    out[g * 2 + 0] = s0;
    out[g * 2 + 1] = s1;
}

extern "C" void kernel_launch(void* const* d_in, const int* in_sizes, int n_in,
                              void* d_out, int out_size, void* d_ws, size_t ws_size,
                              hipStream_t stream)
{
    const float* x         = (const float*)d_in[0];
    const float* edge_attr = (const float*)d_in[1];
    const float* bn_gamma  = (const float*)d_in[2];
    const float* bn_beta   = (const float*)d_in[3];
    const float* bn_mean   = (const float*)d_in[4];
    const float* bn_var    = (const float*)d_in[5];
    const float* Wl        = (const float*)d_in[6];
    const float* bl        = (const float*)d_in[7];
    const float* Wr        = (const float*)d_in[8];
    const float* br        = (const float*)d_in[9];
    const float* We        = (const float*)d_in[10];
    const float* att       = (const float*)d_in[11];
    const float* bias_out  = (const float*)d_in[12];
    const float* Wlin      = (const float*)d_in[13];
    const float* blin      = (const float*)d_in[14];
    const int* edge_index  = (const int*)d_in[15];
    const int* batch       = (const int*)d_in[16];
    float* out = (float*)d_out;

    char* ws = (char*)d_ws;
    unsigned short* Wh    = (unsigned short*)(ws + OFF_WH);
    float* scale          = (float*)(ws + OFF_SCALE);
    float* shift          = (float*)(ws + OFF_SHIFT);
    unsigned short* y     = (unsigned short*)(ws + OFF_Y);
    float* alphaE         = (float*)(ws + OFF_ALPHA);
    float* denom          = (float*)(ws + OFF_DENOM);
    float* accC           = (float*)(ws + OFF_ACC);
    float* pooled         = (float*)(ws + OFF_POOL);
    float* cnt            = (float*)(ws + OFF_CNT);

    k_init<<<1024, 256, 0, stream>>>(Wl, Wr, We, bn_gamma, bn_beta, bn_mean, bn_var,
                                     Wh, scale, shift, denom, accC, pooled, cnt);
    k_node_gemm<<<dim3(782, 2), 512, 0, stream>>>(x, Wh, scale, shift, bl, br, y);
    k_edge<<<6250, 512, 0, stream>>>(edge_attr, Wh, y, edge_index, att, alphaE, denom);
    k_agg<<<2048, 256, 0, stream>>>(alphaE, denom, y, edge_index, accC);
    k_pool<<<782, 256, 0, stream>>>(accC, bias_out, batch, pooled, cnt);
    k_final<<<1, 64, 0, stream>>>(pooled, cnt, Wlin, blin, out);
}